// Round 1
// baseline (42.671 us; speedup 1.0000x reference)
//
#include <hip/hip_runtime.h>

// Lennard-Jones periodic pair energy, B=4, N=4096, D=3.
// Strategy: full NxN evaluation (double-counted, x0.5 in epilogue).
// Coordinates pre-scaled by 1/box so min-image is d -= rint(d).
// Grid: B * (N/TI) * JS blocks; each block = 256 i's (1/thread, regs)
// x 256 j's (staged in LDS, broadcast reads). Deterministic 2-kernel
// reduction via workspace partials (no float atomics).

constexpr int B_ = 4;
constexpr int N_ = 4096;
constexpr int TI = 256;                    // threads per block = i's per block
constexpr int ITILES = N_ / TI;            // 16
constexpr int JS = 16;                     // j-slices per batch
constexpr int JLEN = N_ / JS;              // 256 j's per block
constexpr int BLOCKS_PER_B = ITILES * JS;  // 256
constexpr int NBLK = B_ * BLOCKS_PER_B;    // 1024

__global__ __launch_bounds__(TI) void lj_main(
    const float* __restrict__ x, const float* __restrict__ sigma,
    const float* __restrict__ box, float* __restrict__ partial)
{
    __shared__ float sj[JLEN * 3];
    const int gid = blockIdx.x;
    const int b   = gid / BLOCKS_PER_B;
    const int r   = gid % BLOCKS_PER_B;
    const int it  = r / JS;
    const int js  = r % JS;
    const int tid = threadIdx.x;

    const float bx = box[0];
    const float ib = __builtin_amdgcn_rcpf(bx);   // 1/box (1 ulp, fine at 2% tol)
    const float sg = sigma[0] * ib;
    const float c2 = sg * sg;                     // (sigma/box)^2

    const float* xb = x + (size_t)b * N_ * 3;

    // stage j tile, scaled by 1/box; 768 contiguous floats, coalesced
    const float* xj = xb + js * JLEN * 3;
    #pragma unroll
    for (int k = tid; k < JLEN * 3; k += TI) sj[k] = xj[k] * ib;

    const int i = it * TI + tid;                  // this thread's particle
    const float xi0 = xb[i * 3 + 0] * ib;
    const float xi1 = xb[i * 3 + 1] * ib;
    const float xi2 = xb[i * 3 + 2] * ib;
    __syncthreads();

    const int jb = js * JLEN;
    float acc = 0.f;
    #pragma unroll 4
    for (int jj = 0; jj < JLEN; ++jj) {
        // all lanes read same LDS address -> broadcast, conflict-free
        float dx = xi0 - sj[3 * jj + 0];
        float dy = xi1 - sj[3 * jj + 1];
        float dz = xi2 - sj[3 * jj + 2];
        dx -= rintf(dx);                          // min image (scaled coords)
        dy -= rintf(dy);
        dz -= rintf(dz);
        float r2 = dx * dx + dy * dy + dz * dz;   // scaled r^2
        float t  = c2 * __builtin_amdgcn_rcpf(r2); // (sigma/r)^2
        float s6 = t * t * t;
        float u  = fmaf(s6, s6, -s6);             // s12 - s6
        // self-pair: r2=0 -> u=NaN; cndmask discards it
        acc += (i == jb + jj) ? 0.f : u;
    }

    // block reduction: wave shuffle then cross-wave via LDS
    #pragma unroll
    for (int off = 32; off; off >>= 1) acc += __shfl_down(acc, off);
    __shared__ float wpart[TI / 64];
    if ((tid & 63) == 0) wpart[tid >> 6] = acc;
    __syncthreads();
    if (tid == 0) {
        float s = 0.f;
        #pragma unroll
        for (int w = 0; w < TI / 64; ++w) s += wpart[w];
        partial[gid] = s;
    }
}

__global__ __launch_bounds__(BLOCKS_PER_B) void lj_reduce(
    const float* __restrict__ partial, const float* __restrict__ eps,
    float* __restrict__ out)
{
    const int b = blockIdx.x, t = threadIdx.x;
    float v = partial[b * BLOCKS_PER_B + t];
    #pragma unroll
    for (int off = 32; off; off >>= 1) v += __shfl_down(v, off);
    __shared__ float wpart[BLOCKS_PER_B / 64];
    if ((t & 63) == 0) wpart[t >> 6] = v;
    __syncthreads();
    if (t == 0) {
        float s = 0.f;
        #pragma unroll
        for (int w = 0; w < BLOCKS_PER_B / 64; ++w) s += wpart[w];
        out[b] = s * (2.0f * eps[0]);   // 4*eps * 0.5 (full-matrix double count)
    }
}

extern "C" void kernel_launch(void* const* d_in, const int* in_sizes, int n_in,
                              void* d_out, int out_size, void* d_ws, size_t ws_size,
                              hipStream_t stream) {
    const float* x     = (const float*)d_in[0];
    const float* eps   = (const float*)d_in[1];
    const float* sigma = (const float*)d_in[2];
    const float* box   = (const float*)d_in[3];
    float* out = (float*)d_out;
    float* ws  = (float*)d_ws;   // NBLK floats of partials

    lj_main<<<NBLK, TI, 0, stream>>>(x, sigma, box, ws);
    lj_reduce<<<B_, BLOCKS_PER_B, 0, stream>>>(ws, eps, out);
}

// Round 2
// 23.926 us; speedup vs baseline: 1.7835x; 1.7835x over previous
//
#include <hip/hip_runtime.h>

// Lennard-Jones periodic pair energy, B=4, N=4096, D=3.
// Round 2: triangular tile-pair decomposition (each unordered pair once),
// min-image via min(|d|, 1-|d|) (no rndne), SoA LDS + ds_read_b128,
// 2176 blocks for occupancy. Deterministic 2-kernel reduction.

constexpr int B_ = 4;
constexpr int N_ = 4096;
constexpr int TI = 256;                    // threads per block = i-tile size
constexpr int NTILE = N_ / TI;             // 16 tiles
constexpr int NPAIR = NTILE * (NTILE + 1) / 2;  // 136 tile-pairs (it<=jt)
constexpr int NSUB = 4;                    // j sub-slices per tile-pair
constexpr int JL = TI / NSUB;              // 64 j's per block
constexpr int TASKS_PER_B = NPAIR * NSUB;  // 544
constexpr int NBLK = B_ * TASKS_PER_B;     // 2176

template<bool DIAG>
__device__ __forceinline__ void tile_loop(
    const float (*__restrict__ sj)[JL], float xi0, float xi1, float xi2,
    int selfj, float c2, float& out12, float& out6)
{
    float a12[2] = {0.f, 0.f}, a6[2] = {0.f, 0.f};
    #pragma unroll 4
    for (int j4 = 0; j4 < JL; j4 += 4) {
        float jx[4], jy[4], jz[4];
        *(float4*)jx = *(const float4*)&sj[0][j4];   // broadcast b128 reads
        *(float4*)jy = *(const float4*)&sj[1][j4];
        *(float4*)jz = *(const float4*)&sj[2][j4];
        #pragma unroll
        for (int u = 0; u < 4; ++u) {
            float dx = xi0 - jx[u];
            float dy = xi1 - jy[u];
            float dz = xi2 - jz[u];
            // min-image in scaled coords: |d|<1 -> d_min = min(|d|, 1-|d|)
            float wx = fminf(fabsf(dx), 1.0f - fabsf(dx));
            float wy = fminf(fabsf(dy), 1.0f - fabsf(dy));
            float wz = fminf(fabsf(dz), 1.0f - fabsf(dz));
            float r2 = wx * wx;
            r2 = fmaf(wy, wy, r2);
            r2 = fmaf(wz, wz, r2);
            float t  = c2 * __builtin_amdgcn_rcpf(r2);
            float s6 = t * t * t;
            if (DIAG) s6 = (selfj == j4 + u) ? 0.f : s6;  // mask self-pair
            a12[u & 1] = fmaf(s6, s6, a12[u & 1]);
            a6[u & 1] += s6;
        }
    }
    out12 = a12[0] + a12[1];
    out6  = a6[0] + a6[1];
}

__global__ __launch_bounds__(TI) void lj_main(
    const float* __restrict__ x, const float* __restrict__ sigma,
    const float* __restrict__ box, float* __restrict__ partial)
{
    __shared__ __align__(16) float sj[3][JL];
    const int gid = blockIdx.x;
    const int b   = gid / TASKS_PER_B;
    const int rem = gid % TASKS_PER_B;
    const int pairIdx = rem >> 2;          // /NSUB
    const int sub     = rem & (NSUB - 1);
    // pairIdx -> (it, jt), it<=jt, row-major over triangle
    int it = 0, k = pairIdx;
    while (k >= NTILE - it) { k -= NTILE - it; ++it; }
    const int jt = it + k;
    const int tid = threadIdx.x;

    const float ib = __builtin_amdgcn_rcpf(box[0]);
    const float sg = sigma[0] * ib;
    const float c2 = sg * sg;

    const float* xb = x + (size_t)b * N_ * 3;

    // stage 64 j's (SoA, scaled): 192 contiguous floats
    const float* xj = xb + (jt * TI + sub * JL) * 3;
    if (tid < JL * 3) sj[tid % 3][tid / 3] = xj[tid] * ib;

    const int i = it * TI + tid;
    const float xi0 = xb[i * 3 + 0] * ib;
    const float xi1 = xb[i * 3 + 1] * ib;
    const float xi2 = xb[i * 3 + 2] * ib;
    __syncthreads();

    float s12, s6;
    if (it == jt) {
        tile_loop<true >(sj, xi0, xi1, xi2, tid - sub * JL, c2, s12, s6);
    } else {
        tile_loop<false>(sj, xi0, xi1, xi2, -1, c2, s12, s6);
    }
    float acc = s12 - s6;
    if (it == jt) acc *= 0.5f;             // diag tile double-counted

    // block reduction
    #pragma unroll
    for (int off = 32; off; off >>= 1) acc += __shfl_down(acc, off);
    __shared__ float wpart[TI / 64];
    if ((tid & 63) == 0) wpart[tid >> 6] = acc;
    __syncthreads();
    if (tid == 0) {
        float s = 0.f;
        #pragma unroll
        for (int w = 0; w < TI / 64; ++w) s += wpart[w];
        partial[gid] = s;
    }
}

__global__ __launch_bounds__(256) void lj_reduce(
    const float* __restrict__ partial, const float* __restrict__ eps,
    float* __restrict__ out)
{
    const int b = blockIdx.x, t = threadIdx.x;
    float v = 0.f;
    for (int k = t; k < TASKS_PER_B; k += 256) v += partial[b * TASKS_PER_B + k];
    #pragma unroll
    for (int off = 32; off; off >>= 1) v += __shfl_down(v, off);
    __shared__ float wpart[4];
    if ((t & 63) == 0) wpart[t >> 6] = v;
    __syncthreads();
    if (t == 0) {
        float s = 0.f;
        #pragma unroll
        for (int w = 0; w < 4; ++w) s += wpart[w];
        out[b] = s * (4.0f * eps[0]);      // 4*eps, each pair counted once
    }
}

extern "C" void kernel_launch(void* const* d_in, const int* in_sizes, int n_in,
                              void* d_out, int out_size, void* d_ws, size_t ws_size,
                              hipStream_t stream) {
    const float* x     = (const float*)d_in[0];
    const float* eps   = (const float*)d_in[1];
    const float* sigma = (const float*)d_in[2];
    const float* box   = (const float*)d_in[3];
    float* out = (float*)d_out;
    float* ws  = (float*)d_ws;   // NBLK floats of partials

    lj_main<<<NBLK, TI, 0, stream>>>(x, sigma, box, ws);
    lj_reduce<<<B_, 256, 0, stream>>>(ws, eps, out);
}